// Round 2
// baseline (488.235 us; speedup 1.0000x reference)
//
#include <hip/hip_runtime.h>

#define TT 2048
#define NV 1000

// ---- XLA/Eigen f32 tanh: x*P(x2)/Q(x2), clamped. Matches jnp.tanh's error class. ----
__device__ __forceinline__ float tanh_f32(float x) {
    const float L = 7.90531110763549805f;
    x = fminf(fmaxf(x, -L), L);
    float x2 = x * x;
    float p = -2.76076847742355e-16f;
    p = __builtin_fmaf(p, x2, 2.00018790482477e-13f);
    p = __builtin_fmaf(p, x2, -8.60467152213735e-11f);
    p = __builtin_fmaf(p, x2, 5.12229709037114e-08f);
    p = __builtin_fmaf(p, x2, 1.48572235717979e-05f);
    p = __builtin_fmaf(p, x2, 6.37261928875436e-04f);
    p = __builtin_fmaf(p, x2, 4.89352455891786e-03f);
    float q = 1.19825839466702e-06f;
    q = __builtin_fmaf(q, x2, 1.18534705686654e-04f);
    q = __builtin_fmaf(q, x2, 2.26843463243900e-03f);
    q = __builtin_fmaf(q, x2, 4.89352518554385e-03f);
    float r = __builtin_amdgcn_rcpf(q);
    r = __builtin_fmaf(__builtin_fmaf(-q, r, 1.0f), r, r);  // Newton: <=1 ulp
    return (x * p) * r;
}

// ds_swizzle BitMode helpers (within 32-lane groups): src = ((lane&and)|or)^xor
template <int SRC>  // broadcast lane SRC of each 32-group
__device__ __forceinline__ float bcast32(float x) {
    return __int_as_float(__builtin_amdgcn_ds_swizzle(__float_as_int(x), (SRC << 5)));
}
template <int M>    // lane ^ M within 32-group
__device__ __forceinline__ float sxor32(float x) {
    return __int_as_float(__builtin_amdgcn_ds_swizzle(__float_as_int(x), (M << 10) | 0x1f));
}

// LDS: TAB[1000][32] f32 = s_g*(W_ih.emb[v] + b_ih + b_hh), s_g=0.5 (sigmoid lanes,
// folded exactly: sigma(x)=0.5+0.5*tanh(0.5x) per XLA) or 1.0 (g-gate lanes).
// 128000 B -> 1 block/CU, 512 thr = 8 waves = 2 waves/SIMD, 16 batch rows/block.
extern "C" __global__ void __launch_bounds__(512, 2)
lstm_fused(const int* __restrict__ x, const float* __restrict__ emb,
           const float* __restrict__ W_ih, const float* __restrict__ W_hh,
           const float* __restrict__ b_ih, const float* __restrict__ b_hh,
           const float* __restrict__ W_cls, const float* __restrict__ b_cls,
           float* __restrict__ out)
{
    extern __shared__ float TAB[];  // 32000 floats

    const int tid = threadIdx.x;
    const int g   = tid & 31;   // 0-7: i, 8-15: f, 16-23: g-gate, 24-31: o
    const int grp = tid >> 5;
    const int ty  = g >> 3;

    const float sc = (ty == 2) ? 1.0f : 0.5f;  // exact pow2 pre-scale for tanh-form sigmoid
    const float sa = sc;                       // act = sa*t + sb
    const float sb = (ty == 2) ? 0.0f : 0.5f;

    // ---- phase 1: TAB[v][g] (lane g -> bank g, conflict-free writes) ----
    {
        float wi[8];
        #pragma unroll
        for (int k = 0; k < 8; ++k) wi[k] = W_ih[g * 8 + k];
        const float bs = b_ih[g] + b_hh[g];
        for (int v = grp; v < NV; v += 16) {
            const float4 e0 = *(const float4*)(emb + v * 8);
            const float4 e1 = *(const float4*)(emb + v * 8 + 4);
            float d = bs + e0.x * wi[0] + e0.y * wi[1] + e0.z * wi[2] + e0.w * wi[3]
                         + e1.x * wi[4] + e1.y * wi[5] + e1.z * wi[6] + e1.w * wi[7];
            TAB[v * 32 + g] = sc * d;
        }
    }
    __syncthreads();

    // ---- recurrence: 32 lanes per batch row; h lives on f-lanes (8+j), no LDS h ----
    const int b = blockIdx.x * 16 + grp;
    const int* __restrict__ xrow = x + (size_t)b * TT;

    float w[8];
    #pragma unroll
    for (int k = 0; k < 8; ++k) w[k] = sc * W_hh[g * 8 + k];  // exact (sc is pow2)

    float c  = 0.0f;
    float hn = 0.0f;  // f-lane 8+j holds h[j]; other lanes bounded garbage (unused)

    int4 iA = *(const int4*)(xrow);
    int4 iB = *(const int4*)(xrow + 4);
    float xg0 = TAB[iA.x * 32 + g];   // depth-2 TAB prefetch pipeline
    float xg1 = TAB[iA.y * 32 + g];

#define STEP(XG, NIDX) do {                                                     \
        float u = XG;                                                           \
        u = __builtin_fmaf(w[0], bcast32< 8>(hn), u);                           \
        u = __builtin_fmaf(w[1], bcast32< 9>(hn), u);                           \
        u = __builtin_fmaf(w[2], bcast32<10>(hn), u);                           \
        u = __builtin_fmaf(w[3], bcast32<11>(hn), u);                           \
        u = __builtin_fmaf(w[4], bcast32<12>(hn), u);                           \
        u = __builtin_fmaf(w[5], bcast32<13>(hn), u);                           \
        u = __builtin_fmaf(w[6], bcast32<14>(hn), u);                           \
        u = __builtin_fmaf(w[7], bcast32<15>(hn), u);                           \
        XG = TAB[(NIDX) * 32 + g];          /* prefetch for step t+2 */         \
        float t1  = tanh_f32(u);                                                \
        float act = __builtin_fmaf(sa, t1, sb);  /* sigmoid or tanh */          \
        float vi = sxor32< 8>(act);  /* on f-lane: sigma(i) */                  \
        float vg = sxor32<24>(act);  /* on f-lane: tanh(g)  */                  \
        float vo = sxor32<16>(act);  /* on f-lane: sigma(o) */                  \
        c = __builtin_fmaf(act, c, vi * vg);     /* f: c = sf*c + si*tg */      \
        float th = tanh_f32(c);                                                 \
        hn = vo * th;                            /* f: h = so*tanh(c) */        \
    } while (0)

    for (int t = 0; t < TT; t += 4) {
        const int nb = (t + 8 < TT) ? (t / 4 + 2) : 0;  // clamp tail prefetch
        int4 iN = *(const int4*)(xrow + nb * 4);
        STEP(xg0, iA.z);
        STEP(xg1, iA.w);
        STEP(xg0, iB.x);
        STEP(xg1, iB.y);
        iA = iB; iB = iN;
    }
#undef STEP

    // ---- head: out[b] = 0.5 + 0.5*tanh(0.5*(h.W_cls + b_cls)) ----
    {
        float h0 = bcast32< 8>(hn), h1 = bcast32< 9>(hn);
        float h2 = bcast32<10>(hn), h3 = bcast32<11>(hn);
        float h4 = bcast32<12>(hn), h5 = bcast32<13>(hn);
        float h6 = bcast32<14>(hn), h7 = bcast32<15>(hn);
        if (g == 0) {
            float z = b_cls[0]
                + h0 * W_cls[0] + h1 * W_cls[1] + h2 * W_cls[2] + h3 * W_cls[3]
                + h4 * W_cls[4] + h5 * W_cls[5] + h6 * W_cls[6] + h7 * W_cls[7];
            out[b] = __builtin_fmaf(0.5f, tanh_f32(0.5f * z), 0.5f);
        }
    }
}

extern "C" void kernel_launch(void* const* d_in, const int* in_sizes, int n_in,
                              void* d_out, int out_size, void* d_ws, size_t ws_size,
                              hipStream_t stream)
{
    (void)in_sizes; (void)n_in; (void)d_ws; (void)ws_size; (void)out_size;
    const int*   x     = (const int*)  d_in[0];
    const float* emb   = (const float*)d_in[1];
    const float* W_ih  = (const float*)d_in[2];
    const float* W_hh  = (const float*)d_in[3];
    const float* b_ih  = (const float*)d_in[4];
    const float* b_hh  = (const float*)d_in[5];
    const float* W_cls = (const float*)d_in[6];
    const float* b_cls = (const float*)d_in[7];
    float* out = (float*)d_out;

    const int lds_bytes = NV * 32 * 4;  // 128000 <= 163840 (gfx950 opt-in)
    hipFuncSetAttribute((const void*)lstm_fused,
                        hipFuncAttributeMaxDynamicSharedMemorySize, lds_bytes);

    lstm_fused<<<dim3(256), dim3(512), lds_bytes, stream>>>(
        x, emb, W_ih, W_hh, b_ih, b_hh, W_cls, b_cls, out);
}